// Round 6
// baseline (139.995 us; speedup 1.0000x reference)
//
#include <hip/hip_runtime.h>

#define BATCH 131072
#define IN 128
#define OUT 128
#define PNUM 16
#define GRID 1024
#define ITERS 4            // GRID blocks * 32 rows/iter * ITERS == BATCH
#define LDS_PITCH 136      // f16; 2-way bank aliasing on b128 reads = free

typedef _Float16 f16x8 __attribute__((ext_vector_type(8)));
typedef float f32x4 __attribute__((ext_vector_type(4)));

__device__ __forceinline__ float tanh_fast(float v) {
    float e = __expf(2.0f * v);
    return 1.0f - 2.0f * __builtin_amdgcn_rcpf(e + 1.0f);
}

// w[o*IN + i] = (f16) sum_p coef[o][i][p]; 64B contiguous per thread, coalesced.
__global__ __launch_bounds__(256) void prep_w_kernel(const float* __restrict__ coef,
                                                     _Float16* __restrict__ w) {
    int t = blockIdx.x * blockDim.x + threadIdx.x;
    const float4* p = (const float4*)(coef + (size_t)t * PNUM);
    float4 a = p[0], b = p[1], c = p[2], d = p[3];
    float s = (a.x + a.y + a.z + a.w) + (b.x + b.y + b.z + b.w)
            + (c.x + c.y + c.z + c.w) + (d.x + d.y + d.z + d.w);
    w[t] = (_Float16)s;
}

// Streaming GEMM, tuned for occupancy (the R2..R5 lesson: 32 waves/CU beats
// every fancier structure at lower occupancy).
// Block = 512 threads (8 waves) = 2 row-groups x 4 col-quarters; 32 rows/iter.
// Grid 1024 = 4 blocks/CU (LDS 34.8KB x4 = 139KB) -> 32 waves/CU, VGPR cap 64.
// acc is only 8 regs (32-col quarter) so ~40 regs remain for in-flight x loads.
// ITERS=4: next-iter x reads overlap current-iter out writes (full-duplex HBM).
// MFMA operands swapped (w as A, tanh(x) as B) -> D[ocol][batch] -> each lane
// stores 4 consecutive floats: global_store_dwordx4, 4x fewer store insts.
__global__ __launch_bounds__(512, 8) void gemm_tanh_kernel(const float* __restrict__ x,
                                                           const _Float16* __restrict__ w,
                                                           const float* __restrict__ trange,
                                                           float* __restrict__ out) {
    __shared__ _Float16 wlds[OUT * LDS_PITCH];

    const float t = trange[0];
    const int tid  = threadIdx.x;
    const int lane = tid & 63;
    const int wv   = tid >> 6;
    const int rg   = wv >> 2;        // row group 0/1 (16 rows each)
    const int ch   = wv & 3;         // col quarter 0..3 (32 cols each)
    const int m = lane & 15;
    const int q = lane >> 4;

    const size_t row0 = (size_t)blockIdx.x * 32 + rg * 16;

    // issue iter-0 x prefetch first (longest chain)
    float4 xv[8];
    {
        const float* xr = x + (row0 + m) * IN;
#pragma unroll
        for (int ks = 0; ks < 4; ++ks) {
            xv[2 * ks]     = *(const float4*)(xr + ks * 32 + q * 8);
            xv[2 * ks + 1] = *(const float4*)(xr + ks * 32 + q * 8 + 4);
        }
    }

    // stage w (32 KB, L2-resident) into padded LDS; 32 f16 per thread
#pragma unroll
    for (int j = 0; j < 4; ++j) {
        int idx = (j * 512 + tid) * 8;
        int r = idx >> 7;
        int c = idx & 127;
        *(f16x8*)&wlds[r * LDS_PITCH + c] = *(const f16x8*)(w + idx);
    }
    __syncthreads();   // the only barrier in the kernel

#pragma unroll
    for (int i = 0; i < ITERS; ++i) {
        // consume xv -> B fragments (tanh); B[k][n=batch]: lane holds x[m][q*8+j]
        f16x8 af[4];
#pragma unroll
        for (int ks = 0; ks < 4; ++ks) {
            float4 a = xv[2 * ks], b = xv[2 * ks + 1];
            af[ks][0] = (_Float16)tanh_fast(a.x * t);
            af[ks][1] = (_Float16)tanh_fast(a.y * t);
            af[ks][2] = (_Float16)tanh_fast(a.z * t);
            af[ks][3] = (_Float16)tanh_fast(a.w * t);
            af[ks][4] = (_Float16)tanh_fast(b.x * t);
            af[ks][5] = (_Float16)tanh_fast(b.y * t);
            af[ks][6] = (_Float16)tanh_fast(b.z * t);
            af[ks][7] = (_Float16)tanh_fast(b.w * t);
        }

        // issue next-iter x prefetch; overlaps MFMA + stores of this iter
        if (i + 1 < ITERS) {
            const float* xn = x + (row0 + (size_t)(i + 1) * (GRID * 32) + m) * IN;
#pragma unroll
            for (int ks = 0; ks < 4; ++ks) {
                xv[2 * ks]     = *(const float4*)(xn + ks * 32 + q * 8);
                xv[2 * ks + 1] = *(const float4*)(xn + ks * 32 + q * 8 + 4);
            }
        }

        // 8 MFMAs: 2 col-tiles x 4 k-steps; w (A-operand) from LDS.
        // A[i=oc][k]: lane holds w[ch*32 + nt*16 + m][ks*32 + q*8 + j]
        f32x4 acc[2];
        acc[0] = (f32x4){0.f, 0.f, 0.f, 0.f};
        acc[1] = (f32x4){0.f, 0.f, 0.f, 0.f};
#pragma unroll
        for (int ks = 0; ks < 4; ++ks) {
            const int kb = ks * 32 + q * 8;
#pragma unroll
            for (int nt = 0; nt < 2; ++nt) {
                f16x8 bf = *(const f16x8*)&wlds[(ch * 32 + nt * 16 + m) * LDS_PITCH + kb];
                acc[nt] = __builtin_amdgcn_mfma_f32_16x16x32_f16(bf, af[ks], acc[nt], 0, 0, 0);
            }
        }

        // D[oc_local = q*4+r][batch = m] -> lane stores float4 at
        // out[row0 + i*32768 + m][ch*32 + nt*16 + q*4]
        float* orow = out + (row0 + (size_t)i * (GRID * 32) + m) * OUT + ch * 32 + q * 4;
        *(f32x4*)(orow)      = acc[0];
        *(f32x4*)(orow + 16) = acc[1];
    }
}

extern "C" void kernel_launch(void* const* d_in, const int* in_sizes, int n_in,
                              void* d_out, int out_size, void* d_ws, size_t ws_size,
                              hipStream_t stream) {
    const float* x    = (const float*)d_in[0];
    const float* coef = (const float*)d_in[1];
    const float* tr   = (const float*)d_in[2];
    float* out = (float*)d_out;
    _Float16* w = (_Float16*)d_ws;   // 32 KB scratch, L2-resident

    prep_w_kernel<<<(OUT * IN) / 256, 256, 0, stream>>>(coef, w);
    gemm_tanh_kernel<<<GRID, 512, 0, stream>>>(x, w, tr, out);
}